// Round 1
// 248.026 us; speedup vs baseline: 1.0050x; 1.0050x over previous
//
#include <hip/hip_runtime.h>
#include <math.h>

constexpr int DIM = 64;
constexpr int S = 8;
constexpr int WPB = 16;                // waves per block (1024 threads)
constexpr int BLOCK = WPB * 64;
constexpr int GRID = 512;              // 2 blocks/CU x 256 CU; grid-stride over batch

typedef __attribute__((ext_vector_type(8))) __bf16 bf16x8;   // 4 VGPRs: MFMA A/B frag
typedef __attribute__((ext_vector_type(4))) float  f32x4;    // MFMA C/D frag

// pure-LDS fence: orders ds ops without draining vmcnt (keeps u/v prefetch in flight)
#define LDS_FENCE() asm volatile("s_waitcnt lgkmcnt(0)" ::: "memory")

// DPP quad-perm lane exchange (VALU pipe, not DS) — correctness verified R3-R6
template <int CTRL>
__device__ __forceinline__ float dppx(float x) {
    return __builtin_bit_cast(float,
        __builtin_amdgcn_mov_dpp(__builtin_bit_cast(int, x), CTRL, 0xf, 0xf, true));
}
#define XOR1 0xB1   // quad_perm(1,0,3,2)
#define XOR2 0x4E   // quad_perm(2,3,0,1)

// pack two floats as bf16 (RNE-ish) into one dword: lo=a, hi=b
__device__ __forceinline__ unsigned pk_bf16(float a, float b) {
    unsigned ua = __builtin_bit_cast(unsigned, a);
    unsigned ub = __builtin_bit_cast(unsigned, b);
    ua = (ua + 0x8000u) >> 16;
    ub = (ub + 0x8000u) & 0xffff0000u;
    return ua | ub;
}

// 8-way softmax over lanes' (lane&7) scores; broadcasts w[0..7] to all lanes.
__device__ __forceinline__ void octet_softmax(float sc, float* wout) {
    float m = sc;
    m = fmaxf(m, dppx<XOR1>(m));
    m = fmaxf(m, dppx<XOR2>(m));
    m = fmaxf(m, __shfl_xor(m, 4));
    float e = __expf(sc - m);
    float s = e;
    s += dppx<XOR1>(s);
    s += dppx<XOR2>(s);
    s += __shfl_xor(s, 4);
    float w = e / s;
    #pragma unroll
    for (int k = 0; k < 8; k++) wout[k] = __shfl(w, k);   // lane k (mod 8) holds s=k
}

// h = relu(x @ W + b) via MFMA 16x16x32 bf16.
// x (fp32, lane=dim) is split into bf16 hi + bf16 residual, written to this wave's
// LDS row, then read back as A-fragments with all 16 rows = x (per-lanegroup
// broadcast read) so every lane's acc regs hold valid h. W is pre-staged in LDS in
// B-frag layout. Two chained MFMAs (hi, lo) per fragment keep x at fp32 accuracy,
// so total rounding error == old fp32-x * bf16-W path (absmax 0.031 lineage).
__device__ __forceinline__ void matvec_h(
    float xv, int lane, unsigned short* xw,
    const bf16x8* xa00, const bf16x8* xa01,    // kt=0: hi, lo
    const bf16x8* xa10, const bf16x8* xa11,    // kt=1: hi, lo
    const unsigned* bf,                        // &sBF[lane*4]; + kt*1024 + nt*256
    float b0, float b1, float b2, float b3,
    float& h0, float& h1, float& h2, float& h3)
{
    LDS_FENCE();                               // WAR: prior A-frag reads done before overwrite
    const unsigned xb = __builtin_bit_cast(unsigned, xv);
    const unsigned hb = (xb + 0x8000u) & 0xffff0000u;
    const float xl = xv - __builtin_bit_cast(float, hb);
    xw[lane]      = (unsigned short)(hb >> 16);
    xw[64 + lane] = (unsigned short)((__builtin_bit_cast(unsigned, xl) + 0x8000u) >> 16);
    LDS_FENCE();                               // RAW: writes visible to whole wave

    f32x4 a0 = {0.f, 0.f, 0.f, 0.f};
    f32x4 a1 = a0, a2 = a0, a3 = a0;

    // K-tile 0 (k = 0..31)
    {
        const bf16x8 ah = *xa00, al = *xa01;
        const bf16x8 w0 = *(const bf16x8*)(bf);
        const bf16x8 w1 = *(const bf16x8*)(bf + 256);
        const bf16x8 w2 = *(const bf16x8*)(bf + 512);
        const bf16x8 w3 = *(const bf16x8*)(bf + 768);
        a0 = __builtin_amdgcn_mfma_f32_16x16x32_bf16(ah, w0, a0, 0, 0, 0);
        a0 = __builtin_amdgcn_mfma_f32_16x16x32_bf16(al, w0, a0, 0, 0, 0);
        a1 = __builtin_amdgcn_mfma_f32_16x16x32_bf16(ah, w1, a1, 0, 0, 0);
        a1 = __builtin_amdgcn_mfma_f32_16x16x32_bf16(al, w1, a1, 0, 0, 0);
        a2 = __builtin_amdgcn_mfma_f32_16x16x32_bf16(ah, w2, a2, 0, 0, 0);
        a2 = __builtin_amdgcn_mfma_f32_16x16x32_bf16(al, w2, a2, 0, 0, 0);
        a3 = __builtin_amdgcn_mfma_f32_16x16x32_bf16(ah, w3, a3, 0, 0, 0);
        a3 = __builtin_amdgcn_mfma_f32_16x16x32_bf16(al, w3, a3, 0, 0, 0);
    }
    // K-tile 1 (k = 32..63)
    {
        const bf16x8 ah = *xa10, al = *xa11;
        const bf16x8 w0 = *(const bf16x8*)(bf + 1024);
        const bf16x8 w1 = *(const bf16x8*)(bf + 1280);
        const bf16x8 w2 = *(const bf16x8*)(bf + 1536);
        const bf16x8 w3 = *(const bf16x8*)(bf + 1792);
        a0 = __builtin_amdgcn_mfma_f32_16x16x32_bf16(ah, w0, a0, 0, 0, 0);
        a0 = __builtin_amdgcn_mfma_f32_16x16x32_bf16(al, w0, a0, 0, 0, 0);
        a1 = __builtin_amdgcn_mfma_f32_16x16x32_bf16(ah, w1, a1, 0, 0, 0);
        a1 = __builtin_amdgcn_mfma_f32_16x16x32_bf16(al, w1, a1, 0, 0, 0);
        a2 = __builtin_amdgcn_mfma_f32_16x16x32_bf16(ah, w2, a2, 0, 0, 0);
        a2 = __builtin_amdgcn_mfma_f32_16x16x32_bf16(al, w2, a2, 0, 0, 0);
        a3 = __builtin_amdgcn_mfma_f32_16x16x32_bf16(ah, w3, a3, 0, 0, 0);
        a3 = __builtin_amdgcn_mfma_f32_16x16x32_bf16(al, w3, a3, 0, 0, 0);
    }

    // all 16 C rows equal (A rows replicated) -> reg 0 of each N-tile is h[16*nt + (lane&15)]
    h0 = fmaxf(a0[0] + b0, 0.f);
    h1 = fmaxf(a1[0] + b1, 0.f);
    h2 = fmaxf(a2[0] + b2, 0.f);
    h3 = fmaxf(a3[0] + b3, 0.f);
}

__global__ __launch_bounds__(BLOCK, 4)   // cap VGPR at 128 -> >=16 waves/CU
void sestkgcn_kernel(
    const int*   __restrict__ u_idx,
    const int*   __restrict__ v_idx,
    const float* __restrict__ usr_feat,
    const float* __restrict__ item_feat,
    const float* __restrict__ rel_feat,
    const int*   __restrict__ neigh_uu,
    const float* __restrict__ neigh_uu_st,
    const int*   __restrict__ neigh_ui,
    const float* __restrict__ neigh_ui_rat,
    const float* __restrict__ neigh_ui_vot,
    const float* __restrict__ neigh_ui_tim,
    const int*   __restrict__ neigh_iu,
    const float* __restrict__ neigh_iu_rat,
    const float* __restrict__ neigh_iu_vot,
    const float* __restrict__ neigh_iu_tim,
    const int*   __restrict__ neigh_ii,
    const int*   __restrict__ neigh_ir,
    const float* __restrict__ Wu,
    const float* __restrict__ bu,
    const float* __restrict__ Wv,
    const float* __restrict__ bv,
    float*       __restrict__ out,
    int n)
{
    // B-fragment layout for mfma_f32_16x16x32_bf16, frag f = kt*4+nt:
    //   sBF[(f*64 + lane)*4 + d] packs W[32*kt + 8*(lane>>4) + 2d][16*nt + (lane&15)] (lo)
    //   and row+1 (hi) — element j of the lane's 8 bf16 is k = 32*kt + 8*(lane>>4) + j.
    __shared__ unsigned sBFu[2048];
    __shared__ unsigned sBFv[2048];
    // per-wave x: shorts [0..63] = bf16 hi(x[k]), [64..127] = bf16 residual lo(x[k])
    __shared__ __align__(16) unsigned short sX[WPB][128];

    const int tid = threadIdx.x;
    for (int i = tid; i < 2048; i += BLOCK) {
        const int d = i & 3, l = (i >> 2) & 63, f = i >> 8;
        const int row = ((f >> 2) << 5) + ((l >> 4) << 3) + (d << 1);
        const int col = ((f & 3) << 4) + (l & 15);
        sBFu[i] = pk_bf16(Wu[row * DIM + col], Wu[(row + 1) * DIM + col]);
        sBFv[i] = pk_bf16(Wv[row * DIM + col], Wv[(row + 1) * DIM + col]);
    }
    __syncthreads();

    const int wave = tid >> 6;
    const int lane = tid & 63;
    const int ls   = lane & 7;
    const int g    = lane >> 4;    // MFMA lanegroup
    const int c    = lane & 15;    // MFMA column within N-tile

    unsigned short* xw = &sX[wave][0];
    const bf16x8* xa00 = (const bf16x8*)&sX[wave][g * 8];        // kt0 hi
    const bf16x8* xa01 = (const bf16x8*)&sX[wave][64 + g * 8];   // kt0 lo
    const bf16x8* xa10 = (const bf16x8*)&sX[wave][32 + g * 8];   // kt1 hi
    const bf16x8* xa11 = (const bf16x8*)&sX[wave][96 + g * 8];   // kt1 lo
    const unsigned* bfu = &sBFu[lane * 4];
    const unsigned* bfv = &sBFv[lane * 4];

    // bias in C-frag layout: lane (any group) needs dims {c, 16+c, 32+c, 48+c}
    const float bu0 = bu[c], bu1 = bu[c + 16], bu2 = bu[c + 32], bu3 = bu[c + 48];
    const float bv0 = bv[c], bv1 = bv[c + 16], bv2 = bv[c + 32], bv3 = bv[c + 48];

    const int stride = GRID * WPB;
    int b = blockIdx.x * WPB + wave;
    if (b >= n) return;

    int u = u_idx[b];
    int v = v_idx[b];

    while (b < n) {
        const int b2 = b + stride;
        const int bc = (b2 < n) ? b2 : b;
        const int u_nxt = u_idx[bc];
        const int v_nxt = v_idx[bc];

        const unsigned u8 = (unsigned)u << 3, v8 = (unsigned)v << 3;

        const float u_d = usr_feat[((unsigned)u << 6) | (unsigned)lane];
        const float v_d = item_feat[((unsigned)v << 6) | (unsigned)lane];

        const float sc_uu = neigh_uu_st[u8 + ls];
        const float sc_ui = neigh_ui_rat[u8 + ls] * neigh_ui_vot[u8 + ls] * neigh_ui_tim[u8 + ls];
        const float sc_iu = neigh_iu_rat[v8 + ls] * neigh_iu_vot[v8 + ls] * neigh_iu_tim[v8 + ls];

        // ---------------- user side ----------------
        float w[S];
        octet_softmax(sc_uu, w);
        float agg_uu = 0.f;
        {
            const int4 i0 = ((const int4*)(neigh_uu + u8))[0];
            const int4 i1 = ((const int4*)(neigh_uu + u8))[1];
            const int ni[S] = {i0.x, i0.y, i0.z, i0.w, i1.x, i1.y, i1.z, i1.w};
            float r[S];
            #pragma unroll
            for (int s = 0; s < S; s++) r[s] = usr_feat[((unsigned)ni[s] << 6) | (unsigned)lane];
            #pragma unroll
            for (int s = 0; s < S; s++) agg_uu = fmaf(w[s], r[s], agg_uu);
        }

        octet_softmax(sc_ui, w);
        float agg_ui = 0.f;
        {
            const int4 i0 = ((const int4*)(neigh_ui + u8))[0];
            const int4 i1 = ((const int4*)(neigh_ui + u8))[1];
            const int ni[S] = {i0.x, i0.y, i0.z, i0.w, i1.x, i1.y, i1.z, i1.w};
            float r[S];
            #pragma unroll
            for (int s = 0; s < S; s++) r[s] = item_feat[((unsigned)ni[s] << 6) | (unsigned)lane];
            #pragma unroll
            for (int s = 0; s < S; s++) agg_ui = fmaf(w[s], r[s], agg_ui);
        }

        // user_h = relu(x @ Wu + bu) via MFMA
        float hu0, hu1, hu2, hu3;
        matvec_h(u_d + agg_uu + agg_ui, lane, xw, xa00, xa01, xa10, xa11,
                 bfu, bu0, bu1, bu2, bu3, hu0, hu1, hu2, hu3);

        // ---------------- item side ----------------
        octet_softmax(sc_iu, w);
        float agg_iu = 0.f;
        {
            const int4 i0 = ((const int4*)(neigh_iu + v8))[0];
            const int4 i1 = ((const int4*)(neigh_iu + v8))[1];
            const int ni[S] = {i0.x, i0.y, i0.z, i0.w, i1.x, i1.y, i1.z, i1.w};
            float r[S];
            #pragma unroll
            for (int s = 0; s < S; s++) r[s] = usr_feat[((unsigned)ni[s] << 6) | (unsigned)lane];
            #pragma unroll
            for (int s = 0; s < S; s++) agg_iu = fmaf(w[s], r[s], agg_iu);
        }

        // KG attention: merge 8 dot-products so lane holds total for s=lane&7
        {
            const int4 r0 = ((const int4*)(neigh_ir + v8))[0];
            const int4 r1 = ((const int4*)(neigh_ir + v8))[1];
            const int nr[S] = {r0.x, r0.y, r0.z, r0.w, r1.x, r1.y, r1.z, r1.w};
            float p[S];
            #pragma unroll
            for (int s = 0; s < S; s++) p[s] = u_d * rel_feat[((unsigned)nr[s] << 6) | (unsigned)lane];

            float m1[4];
            #pragma unroll
            for (int i = 0; i < 4; i++) {
                float lo = (lane & 1) ? p[2 * i + 1] : p[2 * i];
                float hi = (lane & 1) ? p[2 * i]     : p[2 * i + 1];
                m1[i] = lo + dppx<XOR1>(hi);
            }
            float m2[2];
            #pragma unroll
            for (int i = 0; i < 2; i++) {
                float lo = (lane & 2) ? m1[2 * i + 1] : m1[2 * i];
                float hi = (lane & 2) ? m1[2 * i]     : m1[2 * i + 1];
                m2[i] = lo + dppx<XOR2>(hi);
            }
            float lo = (lane & 4) ? m2[1] : m2[0];
            float hi = (lane & 4) ? m2[0] : m2[1];
            float att = lo + __shfl_xor(hi, 4);
            att += __shfl_xor(att, 8);
            att += __shfl_xor(att, 16);
            att += __shfl_xor(att, 32);
            octet_softmax(att, w);
        }
        float agg_ii = 0.f;
        {
            const int4 i0 = ((const int4*)(neigh_ii + v8))[0];
            const int4 i1 = ((const int4*)(neigh_ii + v8))[1];
            const int ni[S] = {i0.x, i0.y, i0.z, i0.w, i1.x, i1.y, i1.z, i1.w};
            float r[S];
            #pragma unroll
            for (int s = 0; s < S; s++) r[s] = item_feat[((unsigned)ni[s] << 6) | (unsigned)lane];
            #pragma unroll
            for (int s = 0; s < S; s++) agg_ii = fmaf(w[s], r[s], agg_ii);
        }

        // item_h = relu(x @ Wv + bv) via MFMA
        float hv0, hv1, hv2, hv3;
        matvec_h(v_d + agg_iu + agg_ii, lane, xw, xa00, xa01, xa10, xa11,
                 bfv, bv0, bv1, bv2, bv3, hv0, hv1, hv2, hv3);

        // score = sigmoid(dot(user_h, item_h)) * 5 — h lives in C-frag layout:
        // lane holds dims {c, 16+c, 32+c, 48+c}; reduce over the 16 columns.
        float p = hu0 * hv0 + hu1 * hv1 + hu2 * hv2 + hu3 * hv3;
        p += dppx<XOR1>(p);
        p += dppx<XOR2>(p);
        p += __shfl_xor(p, 4);
        p += __shfl_xor(p, 8);
        if (lane == 0) out[b] = 5.0f / (1.0f + __expf(-p));

        b = b2;
        u = u_nxt;
        v = v_nxt;
    }
}

extern "C" void kernel_launch(void* const* d_in, const int* in_sizes, int n_in,
                              void* d_out, int out_size, void* d_ws, size_t ws_size,
                              hipStream_t stream) {
    const int*   u_idx        = (const int*)  d_in[0];
    const int*   v_idx        = (const int*)  d_in[1];
    const float* usr_feat     = (const float*)d_in[2];
    const float* item_feat    = (const float*)d_in[3];
    const float* rel_feat     = (const float*)d_in[4];
    const int*   neigh_uu     = (const int*)  d_in[5];
    const float* neigh_uu_st  = (const float*)d_in[6];
    const int*   neigh_ui     = (const int*)  d_in[7];
    const float* neigh_ui_rat = (const float*)d_in[8];
    const float* neigh_ui_vot = (const float*)d_in[9];
    const float* neigh_ui_tim = (const float*)d_in[10];
    const int*   neigh_iu     = (const int*)  d_in[11];
    const float* neigh_iu_rat = (const float*)d_in[12];
    const float* neigh_iu_vot = (const float*)d_in[13];
    const float* neigh_iu_tim = (const float*)d_in[14];
    const int*   neigh_ii     = (const int*)  d_in[15];
    const int*   neigh_ir     = (const int*)  d_in[16];
    const float* Wu           = (const float*)d_in[17];
    const float* bu           = (const float*)d_in[18];
    const float* Wv           = (const float*)d_in[19];
    const float* bv           = (const float*)d_in[20];
    float*       out          = (float*)d_out;

    const int n = in_sizes[0];
    int blocks = (n + WPB - 1) / WPB;
    if (blocks > GRID) blocks = GRID;
    sestkgcn_kernel<<<blocks, BLOCK, 0, stream>>>(
        u_idx, v_idx, usr_feat, item_feat, rel_feat,
        neigh_uu, neigh_uu_st, neigh_ui, neigh_ui_rat, neigh_ui_vot, neigh_ui_tim,
        neigh_iu, neigh_iu_rat, neigh_iu_vot, neigh_iu_tim, neigh_ii, neigh_ir,
        Wu, bu, Wv, bv, out, n);
}